// Round 10
// baseline (220.947 us; speedup 1.0000x reference)
//
#include <hip/hip_runtime.h>
#include <hip/hip_bf16.h>

#define TA_B 2
#define TA_H 16
#define TA_S 2048
#define TA_D 64
#define KTILE 64
#define QB 128
#define BLOCK 512
#define NKT (TA_S / KTILE)

typedef __attribute__((ext_vector_type(4))) float f32x4;
typedef __attribute__((ext_vector_type(8))) short bf16x8;
typedef __attribute__((ext_vector_type(8))) unsigned short u16x8;
typedef __attribute__((ext_vector_type(2))) unsigned int u32x2;

union BF8 { u16x8 u; bf16x8 s; };

__device__ __forceinline__ unsigned short f2bf(float f) {
    union { float f; unsigned int i; } v; v.f = f;
    unsigned int x = v.i;
    unsigned int r = x + 0x7FFFu + ((x >> 16) & 1u);
    return (unsigned short)(r >> 16);
}

// Raw barrier: waits LDS ops only; global prefetch loads stay in flight
// (hipcc's __syncthreads() would drain vmcnt(0) and kill the pipeline).
__device__ __forceinline__ void barrier_lds() {
    asm volatile("s_waitcnt lgkmcnt(0)" ::: "memory");
    __builtin_amdgcn_sched_barrier(0);
    __builtin_amdgcn_s_barrier();
    __builtin_amdgcn_sched_barrier(0);
}

// ---- mask bit-pack: 33.6 MB int32 -> 1 MB bits, via wave ballot ----
__global__ __launch_bounds__(256) void pack_mask(const int* __restrict__ M,
                                                 unsigned long long* __restrict__ Mp) {
    const int nw = TA_B * TA_S * NKT;                    // 131072 words
    const int wavesTotal = (gridDim.x * blockDim.x) >> 6;
    const int wid  = (blockIdx.x * blockDim.x + threadIdx.x) >> 6;
    const int lane = threadIdx.x & 63;
    for (int w = wid; w < nw; w += wavesTotal) {
        int mv = M[(long)w * 64 + lane];
        unsigned long long bits = __ballot(mv != 0);
        if (lane == 0) Mp[w] = bits;
    }
}

template <bool PACKED>
__global__ __launch_bounds__(BLOCK, 4) void ta_fused(
    const float* __restrict__ Qg,
    const float* __restrict__ Kg,
    const float* __restrict__ Vg,
    const float* __restrict__ Tg,
    const int* __restrict__ Mg,
    const unsigned long long* __restrict__ Mp,
    float* __restrict__ Og,
    float* __restrict__ Pg)
{
    // Double-buffered staging (parity = kt&1): one barrier per tile.
    __shared__ unsigned short sKp[2][KTILE][72];   // bf16(K+T): [k][d]
    __shared__ unsigned short sVt[2][TA_D][72];    // bf16 V^T:  [d][k^(d&56)]
    __shared__ unsigned short sP[QB][72];          // bf16 normalized p: [q][k], wave-private rows

    const int tid  = threadIdx.x;
    const int wave = tid >> 6;                  // 0..7
    const int lane = tid & 63;
    const int c    = lane & 15;
    const int g    = lane >> 4;
    const int row0 = tid >> 3;                  // staging row 0..63
    const int cg   = (tid & 7) * 8;             // staging d-chunk

    // Bijective XCD swizzle (512 blocks): XCD x owns wids [x*64, x*64+64).
    const int did = blockIdx.x + 16 * (blockIdx.y + 16 * blockIdx.z);
    const int wid = (did & 7) * 64 + (did >> 3);
    const int q0  = (wid & 15) * QB;
    const int h   = (wid >> 4) & 15;
    const int b   = wid >> 8;

    const long bh    = (long)b * TA_H + h;
    const long xBase = bh * (long)TA_S * TA_D;
    const long pBase = bh * (long)TA_S * TA_S;
    const long mBase = (long)b * (long)TA_S * TA_S;
    const int  wq0   = wave * 16;
    const int  myq   = q0 + wq0 + c;            // this lane's q-row (swapped-QK: q = c)

    // Q fragments, 1/sqrt(64) folded (exact pow2). Lane (c,g): Q[q=myq][d=g*8+i], +32.
    // Serves as the B-operand of the swapped QK ( S^T = Kp * Q^T ).
    bf16x8 qf0, qf1;
    {
        const float* qp = Qg + xBase + (long)myq * TA_D + g * 8;
        f32x4 a0 = *(const f32x4*)(qp);
        f32x4 a1 = *(const f32x4*)(qp + 4);
        f32x4 b0 = *(const f32x4*)(qp + 32);
        f32x4 b1 = *(const f32x4*)(qp + 36);
        BF8 u0, u1;
#pragma unroll
        for (int i = 0; i < 4; ++i) {
            u0.u[i]     = f2bf(a0[i] * 0.125f);
            u0.u[i + 4] = f2bf(a1[i] * 0.125f);
            u1.u[i]     = f2bf(b0[i] * 0.125f);
            u1.u[i + 4] = f2bf(b1[i] * 0.125f);
        }
        qf0 = u0.s; qf1 = u1.s;
    }

    // Staging registers (prefetch depth 1)
    f32x4 kA0, kA1, tA0, tA1, vA0, vA1;

    auto loadKT = [&](int kt) {
        const long o0 = xBase + (long)(kt * KTILE + row0) * TA_D + cg;
        kA0 = *(const f32x4*)(Kg + o0); kA1 = *(const f32x4*)(Kg + o0 + 4);
        tA0 = *(const f32x4*)(Tg + o0); tA1 = *(const f32x4*)(Tg + o0 + 4);
    };
    auto loadV = [&](int kt) {
        const long o0 = xBase + (long)(kt * KTILE + row0) * TA_D + cg;
        vA0 = *(const f32x4*)(Vg + o0); vA1 = *(const f32x4*)(Vg + o0 + 4);
    };
    auto storeKp = [&](int p) {
        u16x8 r0;
#pragma unroll
        for (int i = 0; i < 4; ++i) {
            r0[i]     = f2bf(kA0[i] + tA0[i]);
            r0[i + 4] = f2bf(kA1[i] + tA1[i]);
        }
        *(u16x8*)&sKp[p][row0][cg] = r0;
    };
    auto storeVt = [&](int p) {
        const int kp = row0 ^ cg;               // XOR-chunk swizzle kills 16-way conflict
#pragma unroll
        for (int i = 0; i < 4; ++i) {
            sVt[p][cg + i][kp]     = f2bf(vA0[i]);
            sVt[p][cg + i + 4][kp] = f2bf(vA1[i]);
        }
    };

    // Packed mask word for (myq, kt): bit k of this row's 64-wide tile.
    auto maskWord = [&](int kt) -> unsigned long long {
        if constexpr (PACKED) {
            return Mp[((long)b * TA_S + myq) * NKT + kt];
        } else {
            const int* mp = Mg + mBase + (long)myq * TA_S + kt * KTILE;
            unsigned long long w = 0;
#pragma unroll
            for (int ct = 0; ct < 4; ++ct)
#pragma unroll
                for (int r = 0; r < 4; ++r)
                    w |= mp[ct * 16 + g * 4 + r] ? (1ull << (ct * 16 + g * 4 + r)) : 0ull;
            return w;
        }
    };

    // ---------------- Pass A: l[q] = sum_k mask*exp(s) ----------------
    float lpart = 0.0f;
    loadKT(0);
    for (int kt = 0; kt < NKT; ++kt) {
        const int p = kt & 1;
        storeKp(p);
        loadKT(kt + 1 < NKT ? kt + 1 : 0);   // prefetch stays in flight across raw barrier
        barrier_lds();

        f32x4 acc[4];
#pragma unroll
        for (int ct = 0; ct < 4; ++ct)
#pragma unroll
            for (int j = 0; j < 4; ++j) acc[ct][j] = 0.0f;

        __builtin_amdgcn_s_setprio(1);
#pragma unroll
        for (int kk = 0; kk < 2; ++kk) {
            bf16x8 qa = kk ? qf1 : qf0;
#pragma unroll
            for (int ct = 0; ct < 4; ++ct) {
                BF8 bf; bf.u = *(const u16x8*)&sKp[p][ct * 16 + c][kk * 32 + g * 8];
                // swapped: A = Kp rows (k), B = Q rows (q) -> acc = S^T tile,
                // lane holds S[q=myq][k = kt*64 + ct*16 + g*4 + r]
                acc[ct] = __builtin_amdgcn_mfma_f32_16x16x32_bf16(bf.s, qa, acc[ct], 0, 0, 0);
            }
        }
        __builtin_amdgcn_s_setprio(0);

        const unsigned long long w = maskWord(kt);
#pragma unroll
        for (int ct = 0; ct < 4; ++ct) {
            const unsigned nib = (unsigned)(w >> (ct * 16 + g * 4)) & 0xFu;
#pragma unroll
            for (int r = 0; r < 4; ++r)
                lpart += ((nib >> r) & 1u) ? __expf(acc[ct][r]) : 0.0f;
        }
        // no trailing barrier: next tile writes buffer p^1
    }

    loadV(0);   // KT(0) regs already resident from the wrap-around prefetch

    // row sum: reduce over the 4 g-groups (lanes c, c+16, c+32, c+48)
    float l = lpart;
    l += __shfl_xor(l, 16);
    l += __shfl_xor(l, 32);
    const float invl = (l > 0.0f) ? (1.0f / l) : 0.0f;   // all-masked row -> zeros

    f32x4 oacc[4];
#pragma unroll
    for (int dt = 0; dt < 4; ++dt)
#pragma unroll
        for (int j = 0; j < 4; ++j) oacc[dt][j] = 0.0f;

    // ---------------- Pass B: recompute S^T, p=e*invl, P<-f32x4 direct, O += p*V ----------------
    for (int kt = 0; kt < NKT; ++kt) {
        const int p = kt & 1;
        storeKp(p);
        storeVt(p);
        const int ktn = kt + 1 < NKT ? kt + 1 : 0;
        loadKT(ktn);
        loadV(ktn);
        barrier_lds();

        f32x4 acc[4];
#pragma unroll
        for (int ct = 0; ct < 4; ++ct)
#pragma unroll
            for (int j = 0; j < 4; ++j) acc[ct][j] = 0.0f;

        __builtin_amdgcn_s_setprio(1);
#pragma unroll
        for (int kk = 0; kk < 2; ++kk) {
            bf16x8 qa = kk ? qf1 : qf0;
#pragma unroll
            for (int ct = 0; ct < 4; ++ct) {
                BF8 bf; bf.u = *(const u16x8*)&sKp[p][ct * 16 + c][kk * 32 + g * 8];
                acc[ct] = __builtin_amdgcn_mfma_f32_16x16x32_bf16(bf.s, qa, acc[ct], 0, 0, 0);
            }
        }
        __builtin_amdgcn_s_setprio(0);

        // p[k] = mask*exp(s)*invl: 4 consecutive k per ct ->
        //   f32x4 nt-store straight to P, bf16-pair pack -> one ds_write_b64 to sP.
        const unsigned long long w = maskWord(kt);
        float* prow = Pg + pBase + (long)myq * TA_S + kt * KTILE;
#pragma unroll
        for (int ct = 0; ct < 4; ++ct) {
            const unsigned nib = (unsigned)(w >> (ct * 16 + g * 4)) & 0xFu;
            f32x4 pv;
#pragma unroll
            for (int r = 0; r < 4; ++r) {
                float e = ((nib >> r) & 1u) ? __expf(acc[ct][r]) : 0.0f;
                pv[r] = e * invl;
            }
            __builtin_nontemporal_store(pv, (f32x4*)(prow + ct * 16 + g * 4));
            u32x2 pk;
            pk[0] = (unsigned)f2bf(pv[0]) | ((unsigned)f2bf(pv[1]) << 16);
            pk[1] = (unsigned)f2bf(pv[2]) | ((unsigned)f2bf(pv[3]) << 16);
            *(u32x2*)&sP[wq0 + c][ct * 16 + g * 4] = pk;
        }

        // PV: A = normalized p rows (own wave, [q=c][k=g*8+i]), B = swizzled V^T
        BF8 pa0, pa1;
        pa0.u = *(const u16x8*)&sP[wq0 + c][g * 8];
        pa1.u = *(const u16x8*)&sP[wq0 + c][32 + g * 8];
        __builtin_amdgcn_s_setprio(1);
#pragma unroll
        for (int dt = 0; dt < 4; ++dt) {
            const int dRow = dt * 16 + c;
            const int kc0 = (g * 8) ^ (dRow & 56);
            const int kc1 = (32 + g * 8) ^ (dRow & 56);
            BF8 bv0, bv1;
            bv0.u = *(const u16x8*)&sVt[p][dRow][kc0];
            oacc[dt] = __builtin_amdgcn_mfma_f32_16x16x32_bf16(pa0.s, bv0.s, oacc[dt], 0, 0, 0);
            bv1.u = *(const u16x8*)&sVt[p][dRow][kc1];
            oacc[dt] = __builtin_amdgcn_mfma_f32_16x16x32_bf16(pa1.s, bv1.s, oacc[dt], 0, 0, 0);
        }
        __builtin_amdgcn_s_setprio(0);
        // no trailing barrier: next tile writes buffer p^1
    }

    // O = oacc (p already normalized); C layout: lane holds O[q=wq0+g*4+r][d=dt*16+c]
#pragma unroll
    for (int dt = 0; dt < 4; ++dt) {
#pragma unroll
        for (int r = 0; r < 4; ++r) {
            __builtin_nontemporal_store(
                oacc[dt][r],
                &Og[xBase + (long)(q0 + wq0 + g * 4 + r) * TA_D + dt * 16 + c]);
        }
    }
}

extern "C" void kernel_launch(void* const* d_in, const int* in_sizes, int n_in,
                              void* d_out, int out_size, void* d_ws, size_t ws_size,
                              hipStream_t stream) {
    const float* Q = (const float*)d_in[0];
    const float* K = (const float*)d_in[1];
    const float* V = (const float*)d_in[2];
    const float* T = (const float*)d_in[3];
    const int*   M = (const int*)d_in[4];

    float* O = (float*)d_out;
    float* P = O + (long)TA_B * TA_H * TA_S * TA_D;

    unsigned long long* Mp = (unsigned long long*)d_ws;
    const size_t needWs = (size_t)TA_B * TA_S * NKT * sizeof(unsigned long long);  // 1 MB

    dim3 grid(TA_S / QB, TA_H, TA_B);   // 16 x 16 x 2 = 512 blocks
    dim3 block(BLOCK);

    if (ws_size >= needWs) {
        hipLaunchKernelGGL(pack_mask, dim3(512), dim3(256), 0, stream, M, Mp);
        hipLaunchKernelGGL(ta_fused<true>, grid, block, 0, stream, Q, K, V, T, M, Mp, O, P);
    } else {
        hipLaunchKernelGGL(ta_fused<false>, grid, block, 0, stream, Q, K, V, T, M, Mp, O, P);
    }
}

// Round 11
// 193.119 us; speedup vs baseline: 1.1441x; 1.1441x over previous
//
#include <hip/hip_runtime.h>
#include <hip/hip_bf16.h>

#define TA_B 2
#define TA_H 16
#define TA_S 2048
#define TA_D 64
#define KTILE 64
#define QB 128
#define BLOCK 512
#define NKT (TA_S / KTILE)

typedef __attribute__((ext_vector_type(4))) float f32x4;
typedef __attribute__((ext_vector_type(8))) short bf16x8;
typedef __attribute__((ext_vector_type(8))) unsigned short u16x8;
typedef __attribute__((ext_vector_type(4))) unsigned short u16x4;
typedef __attribute__((ext_vector_type(2))) unsigned int u32x2;

union BF8 { u16x8 u; bf16x8 s; };

__device__ __forceinline__ unsigned short f2bf(float f) {
    union { float f; unsigned int i; } v; v.f = f;
    unsigned int x = v.i;
    unsigned int r = x + 0x7FFFu + ((x >> 16) & 1u);
    return (unsigned short)(r >> 16);
}
__device__ __forceinline__ float bf2f(unsigned short u) {
    union { unsigned int i; float f; } v; v.i = ((unsigned int)u) << 16; return v.f;
}

// Raw barrier: waits LDS ops only; global prefetch loads stay in flight
// (hipcc's __syncthreads() would drain vmcnt(0) and kill the pipeline).
__device__ __forceinline__ void barrier_lds() {
    asm volatile("s_waitcnt lgkmcnt(0)" ::: "memory");
    __builtin_amdgcn_sched_barrier(0);
    __builtin_amdgcn_s_barrier();
    __builtin_amdgcn_sched_barrier(0);
}

// ---- mask bit-pack: 33.6 MB int32 -> 1 MB bits, via wave ballot ----
__global__ __launch_bounds__(256) void pack_mask(const int* __restrict__ M,
                                                 unsigned long long* __restrict__ Mp) {
    const int nw = TA_B * TA_S * NKT;                    // 131072 words
    const int wavesTotal = (gridDim.x * blockDim.x) >> 6;
    const int wid  = (blockIdx.x * blockDim.x + threadIdx.x) >> 6;
    const int lane = threadIdx.x & 63;
    for (int w = wid; w < nw; w += wavesTotal) {
        int mv = M[(long)w * 64 + lane];
        unsigned long long bits = __ballot(mv != 0);
        if (lane == 0) Mp[w] = bits;
    }
}

template <bool PACKED>
__global__ __launch_bounds__(BLOCK, 4) void ta_fused(
    const float* __restrict__ Qg,
    const float* __restrict__ Kg,
    const float* __restrict__ Vg,
    const float* __restrict__ Tg,
    const int* __restrict__ Mg,
    const unsigned long long* __restrict__ Mp,
    float* __restrict__ Og,
    float* __restrict__ Pg)
{
    // Double-buffered staging (parity = kt&1): one barrier per tile.
    __shared__ unsigned short sKp[2][KTILE][72];   // bf16(K+T): [k][d]
    __shared__ unsigned short sVt[2][TA_D][72];    // bf16 V^T:  [d][k^(d&56)]
    __shared__ unsigned short sP[QB][72];          // bf16 normalized p: [q][k], wave-private rows

    const int tid  = threadIdx.x;
    const int wave = tid >> 6;                  // 0..7
    const int lane = tid & 63;
    const int c    = lane & 15;
    const int g    = lane >> 4;
    const int row0 = tid >> 3;                  // staging row 0..63
    const int cg   = (tid & 7) * 8;             // staging d-chunk

    // Bijective XCD swizzle (512 blocks): XCD x owns wids [x*64, x*64+64).
    const int did = blockIdx.x + 16 * (blockIdx.y + 16 * blockIdx.z);
    const int wid = (did & 7) * 64 + (did >> 3);
    const int q0  = (wid & 15) * QB;
    const int h   = (wid >> 4) & 15;
    const int b   = wid >> 8;

    const long bh    = (long)b * TA_H + h;
    const long xBase = bh * (long)TA_S * TA_D;
    const long pBase = bh * (long)TA_S * TA_S;
    const long mBase = (long)b * (long)TA_S * TA_S;
    const int  wq0   = wave * 16;
    const int  myq   = q0 + wq0 + c;            // this lane's q-row (swapped-QK: q = c)

    // Q fragments, 1/sqrt(64) folded (exact pow2). Lane (c,g): Q[q=myq][d=g*8+i], +32.
    // Serves as the B-operand of the swapped QK ( S^T = Kp * Q^T ).
    bf16x8 qf0, qf1;
    {
        const float* qp = Qg + xBase + (long)myq * TA_D + g * 8;
        f32x4 a0 = *(const f32x4*)(qp);
        f32x4 a1 = *(const f32x4*)(qp + 4);
        f32x4 b0 = *(const f32x4*)(qp + 32);
        f32x4 b1 = *(const f32x4*)(qp + 36);
        BF8 u0, u1;
#pragma unroll
        for (int i = 0; i < 4; ++i) {
            u0.u[i]     = f2bf(a0[i] * 0.125f);
            u0.u[i + 4] = f2bf(a1[i] * 0.125f);
            u1.u[i]     = f2bf(b0[i] * 0.125f);
            u1.u[i + 4] = f2bf(b1[i] * 0.125f);
        }
        qf0 = u0.s; qf1 = u1.s;
    }

    // Staging registers (prefetch depth 1)
    f32x4 kA0, kA1, tA0, tA1, vA0, vA1;

    auto loadKT = [&](int kt) {
        const long o0 = xBase + (long)(kt * KTILE + row0) * TA_D + cg;
        kA0 = *(const f32x4*)(Kg + o0); kA1 = *(const f32x4*)(Kg + o0 + 4);
        tA0 = *(const f32x4*)(Tg + o0); tA1 = *(const f32x4*)(Tg + o0 + 4);
    };
    auto loadV = [&](int kt) {
        const long o0 = xBase + (long)(kt * KTILE + row0) * TA_D + cg;
        vA0 = *(const f32x4*)(Vg + o0); vA1 = *(const f32x4*)(Vg + o0 + 4);
    };
    auto storeKp = [&](int p) {
        u16x8 r0;
#pragma unroll
        for (int i = 0; i < 4; ++i) {
            r0[i]     = f2bf(kA0[i] + tA0[i]);
            r0[i + 4] = f2bf(kA1[i] + tA1[i]);
        }
        *(u16x8*)&sKp[p][row0][cg] = r0;
    };
    auto storeVt = [&](int p) {
        const int kp = row0 ^ cg;               // XOR-chunk swizzle kills 16-way conflict
#pragma unroll
        for (int i = 0; i < 4; ++i) {
            sVt[p][cg + i][kp]     = f2bf(vA0[i]);
            sVt[p][cg + i + 4][kp] = f2bf(vA1[i]);
        }
    };

    // Packed mask word for (myq, kt): bit k of this row's 64-wide tile.
    auto maskWord = [&](int kt) -> unsigned long long {
        if constexpr (PACKED) {
            return Mp[((long)b * TA_S + myq) * NKT + kt];
        } else {
            const int* mp = Mg + mBase + (long)myq * TA_S + kt * KTILE;
            unsigned long long w = 0;
#pragma unroll
            for (int ct = 0; ct < 4; ++ct)
#pragma unroll
                for (int r = 0; r < 4; ++r)
                    w |= mp[ct * 16 + g * 4 + r] ? (1ull << (ct * 16 + g * 4 + r)) : 0ull;
            return w;
        }
    };

    // ---------------- Pass A: l[q] = sum_k mask*exp(s) ----------------
    float lpart = 0.0f;
    loadKT(0);
    for (int kt = 0; kt < NKT; ++kt) {
        const int p = kt & 1;
        storeKp(p);
        loadKT(kt + 1 < NKT ? kt + 1 : 0);   // prefetch stays in flight across raw barrier
        barrier_lds();

        f32x4 acc[4];
#pragma unroll
        for (int ct = 0; ct < 4; ++ct)
#pragma unroll
            for (int j = 0; j < 4; ++j) acc[ct][j] = 0.0f;

        __builtin_amdgcn_s_setprio(1);
#pragma unroll
        for (int kk = 0; kk < 2; ++kk) {
            bf16x8 qa = kk ? qf1 : qf0;
#pragma unroll
            for (int ct = 0; ct < 4; ++ct) {
                BF8 bf; bf.u = *(const u16x8*)&sKp[p][ct * 16 + c][kk * 32 + g * 8];
                // swapped: A = Kp rows (k), B = Q rows (q) -> lane holds
                // S[q=myq][k = kt*64 + ct*16 + g*4 + r]
                acc[ct] = __builtin_amdgcn_mfma_f32_16x16x32_bf16(bf.s, qa, acc[ct], 0, 0, 0);
            }
        }
        __builtin_amdgcn_s_setprio(0);

        const unsigned long long w = maskWord(kt);
#pragma unroll
        for (int ct = 0; ct < 4; ++ct) {
            const unsigned nib = (unsigned)(w >> (ct * 16 + g * 4)) & 0xFu;
#pragma unroll
            for (int r = 0; r < 4; ++r)
                lpart += ((nib >> r) & 1u) ? __expf(acc[ct][r]) : 0.0f;
        }
        // no trailing barrier: next tile writes buffer p^1
    }

    loadV(0);   // KT(0) regs already resident from the wrap-around prefetch

    // row sum: reduce over the 4 g-groups (lanes c, c+16, c+32, c+48)
    float l = lpart;
    l += __shfl_xor(l, 16);
    l += __shfl_xor(l, 32);
    const float invl = (l > 0.0f) ? (1.0f / l) : 0.0f;   // all-masked row -> zeros

    f32x4 oacc[4];
#pragma unroll
    for (int dt = 0; dt < 4; ++dt)
#pragma unroll
        for (int j = 0; j < 4; ++j) oacc[dt][j] = 0.0f;

    // ---------------- Pass B: recompute S^T, p=e*invl -> sP (b64), O += p*V, full-line P store ----------------
    for (int kt = 0; kt < NKT; ++kt) {
        const int p = kt & 1;
        storeKp(p);
        storeVt(p);
        const int ktn = kt + 1 < NKT ? kt + 1 : 0;
        loadKT(ktn);
        loadV(ktn);
        barrier_lds();

        f32x4 acc[4];
#pragma unroll
        for (int ct = 0; ct < 4; ++ct)
#pragma unroll
            for (int j = 0; j < 4; ++j) acc[ct][j] = 0.0f;

        __builtin_amdgcn_s_setprio(1);
#pragma unroll
        for (int kk = 0; kk < 2; ++kk) {
            bf16x8 qa = kk ? qf1 : qf0;
#pragma unroll
            for (int ct = 0; ct < 4; ++ct) {
                BF8 bf; bf.u = *(const u16x8*)&sKp[p][ct * 16 + c][kk * 32 + g * 8];
                acc[ct] = __builtin_amdgcn_mfma_f32_16x16x32_bf16(bf.s, qa, acc[ct], 0, 0, 0);
            }
        }
        __builtin_amdgcn_s_setprio(0);

        // p[k] = mask*exp(s)*invl, packed in pairs -> one ds_write_b64 per ct (wave-private sP).
        const unsigned long long w = maskWord(kt);
#pragma unroll
        for (int ct = 0; ct < 4; ++ct) {
            const unsigned nib = (unsigned)(w >> (ct * 16 + g * 4)) & 0xFu;
            float pv[4];
#pragma unroll
            for (int r = 0; r < 4; ++r) {
                float e = ((nib >> r) & 1u) ? __expf(acc[ct][r]) : 0.0f;
                pv[r] = e * invl;
            }
            u32x2 pk;
            pk[0] = (unsigned)f2bf(pv[0]) | ((unsigned)f2bf(pv[1]) << 16);
            pk[1] = (unsigned)f2bf(pv[2]) | ((unsigned)f2bf(pv[3]) << 16);
            *(u32x2*)&sP[wq0 + c][ct * 16 + g * 4] = pk;
        }

        // PV: A = normalized p rows (own wave, [q=c][k=g*8+i]), B = swizzled V^T
        BF8 pa0, pa1;
        pa0.u = *(const u16x8*)&sP[wq0 + c][g * 8];
        pa1.u = *(const u16x8*)&sP[wq0 + c][32 + g * 8];
        __builtin_amdgcn_s_setprio(1);
#pragma unroll
        for (int dt = 0; dt < 4; ++dt) {
            const int dRow = dt * 16 + c;
            const int kc0 = (g * 8) ^ (dRow & 56);
            const int kc1 = (32 + g * 8) ^ (dRow & 56);
            BF8 bv0, bv1;
            bv0.u = *(const u16x8*)&sVt[p][dRow][kc0];
            oacc[dt] = __builtin_amdgcn_mfma_f32_16x16x32_bf16(pa0.s, bv0.s, oacc[dt], 0, 0, 0);
            bv1.u = *(const u16x8*)&sVt[p][dRow][kc1];
            oacc[dt] = __builtin_amdgcn_mfma_f32_16x16x32_bf16(pa1.s, bv1.s, oacc[dt], 0, 0, 0);
        }
        __builtin_amdgcn_s_setprio(0);

        // P global store: full 256B row-spans per instruction (4 rows x 16 lanes x 16B).
#pragma unroll
        for (int j = 0; j < 4; ++j) {
            const int prow = 4 * j + g;
            u16x4 pv = *(const u16x4*)&sP[wq0 + prow][c * 4];
            f32x4 v;
#pragma unroll
            for (int i = 0; i < 4; ++i) v[i] = bf2f(pv[i]);
            __builtin_nontemporal_store(
                v, (f32x4*)(Pg + pBase + (long)(q0 + wq0 + prow) * TA_S + kt * KTILE + c * 4));
        }
        // no trailing barrier: next tile writes buffer p^1
    }

    // O = oacc (p already normalized); lane holds O[q=wq0+g*4+r][d=dt*16+c]
#pragma unroll
    for (int dt = 0; dt < 4; ++dt) {
#pragma unroll
        for (int r = 0; r < 4; ++r) {
            __builtin_nontemporal_store(
                oacc[dt][r],
                &Og[xBase + (long)(q0 + wq0 + g * 4 + r) * TA_D + dt * 16 + c]);
        }
    }
}

extern "C" void kernel_launch(void* const* d_in, const int* in_sizes, int n_in,
                              void* d_out, int out_size, void* d_ws, size_t ws_size,
                              hipStream_t stream) {
    const float* Q = (const float*)d_in[0];
    const float* K = (const float*)d_in[1];
    const float* V = (const float*)d_in[2];
    const float* T = (const float*)d_in[3];
    const int*   M = (const int*)d_in[4];

    float* O = (float*)d_out;
    float* P = O + (long)TA_B * TA_H * TA_S * TA_D;

    unsigned long long* Mp = (unsigned long long*)d_ws;
    const size_t needWs = (size_t)TA_B * TA_S * NKT * sizeof(unsigned long long);  // 1 MB

    dim3 grid(TA_S / QB, TA_H, TA_B);   // 16 x 16 x 2 = 512 blocks
    dim3 block(BLOCK);

    if (ws_size >= needWs) {
        hipLaunchKernelGGL(pack_mask, dim3(512), dim3(256), 0, stream, M, Mp);
        hipLaunchKernelGGL(ta_fused<true>, grid, block, 0, stream, Q, K, V, T, M, Mp, O, P);
    } else {
        hipLaunchKernelGGL(ta_fused<false>, grid, block, 0, stream, Q, K, V, T, M, Mp, O, P);
    }
}